// Round 11
// baseline (558.123 us; speedup 1.0000x reference)
//
#include <hip/hip_runtime.h>
#include <hip/hip_fp16.h>

// RGCN: out = hetero(relu(hetero(x, W1,b1)), W2,b2)
// Aggregation commutes with @W_r: Z[n] = [rs_in_r[n]*(sum_e rs_out_r[s]*feat[s] + self)]_r,
// layer = bias + Z(Nx384) @ W(384xWC), W in MFMA B-frag layout (fp16 32x32x16).
// R11: FUSED gather+GEMM — block = 32 nodes (one MFMA M-tile); phase 1 gathers
// the 32x384 Z-tile into LDS (full wave per edge, 8-deep unroll, wave-uniform
// esrc -> SMEM loads); phase 2 does 24 MFMAs per wave from the LDS tile.
// Kills the 76 MB/layer Z16 round-trip and 2 launches.
// CSR build: radix partition, zero global atomics (device atomics ~32B fabric wr each).

constexpr int N   = 50000;
constexpr int R   = 3;
constexpr int IN  = 128;
constexpr int HID = 128;
constexpr int OUT = 64;
constexpr int M   = R * N;
constexpr int BK  = 1024;
constexpr int NBKT = (M + BK - 1) / BK;    // 147
constexpr int CHUNK = 8192;
constexpr int KB  = 24;                    // 384/16 k-blocks for MFMA
constexpr int ZP  = 392;                   // LDS row stride (halves): 16B-aligned, 4-way banks max
constexpr int CVT_N4 = N * IN / 4;         // 1.6M float4 groups
constexpr int WPK   = 6 * KB * 64;         // 9216 weight frags
constexpr int WPK_B = (WPK + 255) / 256;   // 36 blocks

typedef _Float16 half8 __attribute__((ext_vector_type(8)));
typedef float floatx16 __attribute__((ext_vector_type(16)));

// ---- prep: bsum (block 0) + wpack (blocks 1..36) + x fp32->fp16 (rest) ----
__global__ void prep_kernel(const float* __restrict__ x,
                            const float* __restrict__ W1, const float* __restrict__ W2,
                            const float* __restrict__ b1, const float* __restrict__ b2,
                            uint2* __restrict__ x16,
                            __half* __restrict__ F1, __half* __restrict__ F2,
                            float* __restrict__ bsum1, float* __restrict__ bsum2) {
    int b = blockIdx.x;
    if (b == 0) {
        int t = threadIdx.x;
        if (t < HID) bsum1[t] = b1[t] + b1[HID + t] + b1[2 * HID + t];
        if (t < OUT) bsum2[t] = b2[t] + b2[OUT + t] + b2[2 * OUT + t];
        return;
    }
    if (b <= WPK_B) {
        int idx = (b - 1) * 256 + threadIdx.x;
        if (idx < 4 * KB * 64) {
            int nt = idx / (KB * 64), rem = idx % (KB * 64);
            int kb = rem / 64, lane = rem % 64;
            int c = nt * 32 + (lane & 31);
            int k0 = kb * 16 + (lane >> 5) * 8;
            __half h[8];
#pragma unroll
            for (int j = 0; j < 8; j++) h[j] = __float2half_rn(W1[(k0 + j) * 128 + c]);
            *(uint4*)(F1 + (size_t)idx * 8) = *(uint4*)h;
        } else if (idx < 6 * KB * 64) {
            int i2 = idx - 4 * KB * 64;
            int nt = i2 / (KB * 64), rem = i2 % (KB * 64);
            int kb = rem / 64, lane = rem % 64;
            int c = nt * 32 + (lane & 31);
            int k0 = kb * 16 + (lane >> 5) * 8;
            __half h[8];
#pragma unroll
            for (int j = 0; j < 8; j++) h[j] = __float2half_rn(W2[(k0 + j) * 64 + c]);
            *(uint4*)(F2 + (size_t)i2 * 8) = *(uint4*)h;
        }
        return;
    }
    int i = (b - 1 - WPK_B) * 256 + threadIdx.x;
    if (i >= CVT_N4) return;
    float4 v = ((const float4*)x)[i];
    __half2 a = __floats2half2_rn(v.x, v.y);
    __half2 c = __floats2half2_rn(v.z, v.w);
    uint2 o;
    o.x = *(unsigned*)&a;
    o.y = *(unsigned*)&c;
    x16[i] = o;
}

// ---- P1: coarse bucket histograms per edge-chunk ----
__global__ __launch_bounds__(256) void p1_kernel(const int* __restrict__ src,
                                                 const int* __restrict__ dst,
                                                 int E, int RE, int nb,
                                                 int* __restrict__ bh) {
    __shared__ int hd[NBKT], hs[NBKT];
    for (int i = threadIdx.x; i < NBKT; i += 256) { hd[i] = 0; hs[i] = 0; }
    __syncthreads();
    int beg = blockIdx.x * CHUNK, end = min(RE, beg + CHUNK);
    for (int g = beg + (int)threadIdx.x; g < end; g += 256) {
        int rb = ((g >= E) + (g >= 2 * E)) * N;
        atomicAdd(&hd[(rb + dst[g]) >> 10], 1);
        atomicAdd(&hs[(rb + src[g]) >> 10], 1);
    }
    __syncthreads();
    for (int i = threadIdx.x; i < NBKT; i += 256) {
        bh[i * nb + blockIdx.x] = hd[i];
        bh[(NBKT + i) * nb + blockIdx.x] = hs[i];
    }
}

// ---- 2-stage exclusive scan (stage-3 folded into consumers) ----
__global__ void scan1_kernel(const int* __restrict__ in, int* __restrict__ out,
                             int* __restrict__ partials, int L) {
    __shared__ int lds[1024];
    int t = threadIdx.x;
    int idx = blockIdx.x * 1024 + t;
    int v = (idx < L) ? in[idx] : 0;
    lds[t] = v;
    __syncthreads();
    for (int off = 1; off < 1024; off <<= 1) {
        int u = (t >= off) ? lds[t - off] : 0;
        __syncthreads();
        lds[t] += u;
        __syncthreads();
    }
    if (idx < L) out[idx] = lds[t] - v;
    if (t == 1023) partials[blockIdx.x] = lds[1023];
}

__global__ void scan2_kernel(int* __restrict__ partials, int nb1) {
    __shared__ int lds[256];
    int t = threadIdx.x;
    int v = (t < nb1) ? partials[t] : 0;
    lds[t] = v;
    __syncthreads();
    for (int off = 1; off < 256; off <<= 1) {
        int u = (t >= off) ? lds[t - off] : 0;
        __syncthreads();
        lds[t] += u;
        __syncthreads();
    }
    if (t < nb1) partials[t] = lds[t] - v;
}

// ---- P3: scatter edges into bucket-sorted buffers via LDS cursors ----
// ebd[pos] = (src<<10)|(dkey&1023); ebs[pos] = skey&1023 (ushort)
__global__ __launch_bounds__(256) void p3_kernel(const int* __restrict__ src,
                                                 const int* __restrict__ dst,
                                                 int E, int RE, int nb,
                                                 const int* __restrict__ scanv,
                                                 const int* __restrict__ partials,
                                                 int* __restrict__ ebd,
                                                 unsigned short* __restrict__ ebs) {
    __shared__ int cd[NBKT], cs[NBKT];
    for (int i = threadIdx.x; i < NBKT; i += 256) {
        int id = i * nb + blockIdx.x;
        int is = (NBKT + i) * nb + blockIdx.x;
        cd[i] = scanv[id] + partials[id >> 10];
        cs[i] = scanv[is] + partials[is >> 10] - RE;
    }
    __syncthreads();
    int beg = blockIdx.x * CHUNK, end = min(RE, beg + CHUNK);
    for (int g = beg + (int)threadIdx.x; g < end; g += 256) {
        int rb = ((g >= E) + (g >= 2 * E)) * N;
        int s  = src[g];
        int kd = rb + dst[g];
        int pd = atomicAdd(&cd[kd >> 10], 1);
        ebd[pd] = (s << 10) | (kd & 1023);
        int ks = rb + s;
        int ps = atomicAdd(&cs[ks >> 10], 1);
        ebs[ps] = (unsigned short)(ks & 1023);
    }
}

// ---- PB-S: per s-bucket exact histogram -> rs_out ----
__global__ __launch_bounds__(1024) void pbs_kernel(const int* __restrict__ scanv,
                                                   const int* __restrict__ partials,
                                                   int nb, int RE,
                                                   const unsigned short* __restrict__ ebs,
                                                   float* __restrict__ rs_out) {
    __shared__ int cnt[BK];
    int t = threadIdx.x;
    int k = blockIdx.x;
    int i0 = (NBKT + k) * nb;
    int segbeg = scanv[i0] + partials[i0 >> 10] - RE;
    int segend;
    if (k == NBKT - 1) segend = RE;
    else {
        int i1 = i0 + nb;
        segend = scanv[i1] + partials[i1 >> 10] - RE;
    }
    cnt[t] = 0;
    __syncthreads();
    for (int e = segbeg + t; e < segend; e += 1024)
        atomicAdd(&cnt[(int)ebs[e]], 1);
    __syncthreads();
    int slot = k * BK + t;
    if (slot < M) rs_out[slot] = rsqrtf((float)(cnt[t] + 1));
}

// ---- PB-D: per d-bucket histogram -> row_ptr/rs_in, scatter coeff-packed esrc ----
__global__ __launch_bounds__(1024) void pbd_kernel(const int* __restrict__ scanv,
                                                   const int* __restrict__ partials,
                                                   int nb, int RE,
                                                   const int* __restrict__ ebd,
                                                   const float* __restrict__ rs_out,
                                                   int* __restrict__ row_ptr,
                                                   float* __restrict__ rs_in,
                                                   unsigned int* __restrict__ esrc) {
    __shared__ int cnt[BK];
    __shared__ int cur[BK];
    int t = threadIdx.x;
    int k = blockIdx.x;
    int i0 = k * nb;
    int segbeg = scanv[i0] + partials[i0 >> 10];
    int segend;
    if (k == NBKT - 1) segend = RE;
    else {
        int i1 = (k + 1) * nb;
        segend = scanv[i1] + partials[i1 >> 10];
    }
    cnt[t] = 0;
    __syncthreads();
    for (int e = segbeg + t; e < segend; e += 1024)
        atomicAdd(&cnt[ebd[e] & 1023], 1);
    __syncthreads();
    int slot = k * BK + t;
    int c = cnt[t];
    cur[t] = c;
    __syncthreads();
    for (int off = 1; off < 1024; off <<= 1) {
        int u = (t >= off) ? cur[t - off] : 0;
        __syncthreads();
        cur[t] += u;
        __syncthreads();
    }
    int excl = cur[t] - c;
    if (slot < M) {
        row_ptr[slot] = segbeg + excl;
        rs_in[slot] = rsqrtf((float)(c + 1));   // +1 self-loop
    }
    if (k == NBKT - 1 && t == 0) row_ptr[M] = RE;
    __syncthreads();
    cur[t] = segbeg + excl;
    __syncthreads();
    for (int e = segbeg + t; e < segend; e += 1024) {
        int v = ebd[e];
        int key = k * BK + (v & 1023);
        int r = (key >= 2 * N) + (key >= N);
        unsigned s = (unsigned)(v >> 10);
        int pos = atomicAdd(&cur[v & 1023], 1);
        __half h = __float2half_rn(rs_out[r * N + s]);
        esrc[pos] = s | ((unsigned)__half_as_ushort(h) << 16);
    }
}

// ---- FUSED gather + MFMA GEMM ----
// Block = 32 nodes (one M-tile), 4 waves x 8 nodes.
// Phase 1: full wave per edge (64 lanes x half2 = 256B row), 8-edge unroll
// (8 rows in flight/lane), wave-uniform esrc/row_ptr -> scalar loads; partial
// Z rows written to LDS tile [32][392] (rows 16B-aligned, <=4-way banks).
// Phase 2: wave w computes col-tile w: 24x mfma_f32_32x32x16_f16, A-frag from
// LDS (A[m=lane&31][k=(lane>>5)*8+j] per kb), B-frag from repacked F; bias
// (+relu,fp16) epilogue. Tail rows (n>=N) leave garbage LDS -> rows are
// independent in MFMA and never stored.
template <int NT, bool H16OUT>
__global__ __launch_bounds__(256) void fused_kernel(const __half* __restrict__ Xh,
                                                    const float* __restrict__ rs_in,
                                                    const float* __restrict__ rs_out,
                                                    const int* __restrict__ row_ptr,
                                                    const unsigned int* __restrict__ esrc,
                                                    const __half* __restrict__ F,
                                                    const float* __restrict__ bias,
                                                    void* __restrict__ outp) {
    __shared__ __half Zt[32 * ZP];
    int wave = threadIdx.x >> 6, lane = threadIdx.x & 63;
    int nbase = blockIdx.x * 32 + wave * 8;
    const __half2 z2 = __float2half2_rn(0.f);
#pragma unroll 1
    for (int i = 0; i < 8; i++) {
        int n = nbase + i;
        if (n >= N) break;
        __half2 xn = *(const __half2*)(Xh + (long)n * 128 + lane * 2);
#pragma unroll 1
        for (int r = 0; r < R; r++) {
            int key = r * N + n;
            int beg = row_ptr[key], end = row_ptr[key + 1];
            __half2 acc = z2;
            int e = beg;
            for (; e + 8 <= end; e += 8) {
                unsigned u0 = esrc[e + 0], u1 = esrc[e + 1], u2 = esrc[e + 2], u3 = esrc[e + 3];
                unsigned u4 = esrc[e + 4], u5 = esrc[e + 5], u6 = esrc[e + 6], u7 = esrc[e + 7];
                __half2 y0 = *(const __half2*)(Xh + (long)(u0 & 0xffffu) * 128 + lane * 2);
                __half2 y1 = *(const __half2*)(Xh + (long)(u1 & 0xffffu) * 128 + lane * 2);
                __half2 y2 = *(const __half2*)(Xh + (long)(u2 & 0xffffu) * 128 + lane * 2);
                __half2 y3 = *(const __half2*)(Xh + (long)(u3 & 0xffffu) * 128 + lane * 2);
                __half2 y4 = *(const __half2*)(Xh + (long)(u4 & 0xffffu) * 128 + lane * 2);
                __half2 y5 = *(const __half2*)(Xh + (long)(u5 & 0xffffu) * 128 + lane * 2);
                __half2 y6 = *(const __half2*)(Xh + (long)(u6 & 0xffffu) * 128 + lane * 2);
                __half2 y7 = *(const __half2*)(Xh + (long)(u7 & 0xffffu) * 128 + lane * 2);
                acc = __hfma2(y0, __half2half2(__ushort_as_half((unsigned short)(u0 >> 16))), acc);
                acc = __hfma2(y1, __half2half2(__ushort_as_half((unsigned short)(u1 >> 16))), acc);
                acc = __hfma2(y2, __half2half2(__ushort_as_half((unsigned short)(u2 >> 16))), acc);
                acc = __hfma2(y3, __half2half2(__ushort_as_half((unsigned short)(u3 >> 16))), acc);
                acc = __hfma2(y4, __half2half2(__ushort_as_half((unsigned short)(u4 >> 16))), acc);
                acc = __hfma2(y5, __half2half2(__ushort_as_half((unsigned short)(u5 >> 16))), acc);
                acc = __hfma2(y6, __half2half2(__ushort_as_half((unsigned short)(u6 >> 16))), acc);
                acc = __hfma2(y7, __half2half2(__ushort_as_half((unsigned short)(u7 >> 16))), acc);
            }
            for (; e < end; e++) {
                unsigned u = esrc[e];
                __half2 y = *(const __half2*)(Xh + (long)(u & 0xffffu) * 128 + lane * 2);
                acc = __hfma2(y, __half2half2(__ushort_as_half((unsigned short)(u >> 16))), acc);
            }
            acc = __hfma2(xn, __float2half2_rn(rs_out[key]), acc);   // self-loop
            acc = __hmul2(acc, __float2half2_rn(rs_in[key]));
            *(__half2*)&Zt[(wave * 8 + i) * ZP + r * 128 + lane * 2] = acc;
        }
    }
    __syncthreads();
    if (wave >= NT) return;

    floatx16 acc;
#pragma unroll
    for (int j = 0; j < 16; j++) acc[j] = 0.f;
    const half8* Bf = (const half8*)F;
#pragma unroll
    for (int kb = 0; kb < KB; kb++) {
        half8 a = *(const half8*)&Zt[(lane & 31) * ZP + kb * 16 + (lane >> 5) * 8];
        half8 b = Bf[(wave * KB + kb) * 64 + lane];
        acc = __builtin_amdgcn_mfma_f32_32x32x16_f16(a, b, acc, 0, 0, 0);
    }
    // C/D map: col=lane&31, row=(reg&3)+8*(reg>>2)+4*(lane>>5)  [m74/m101 verified]
    float bv = bias[wave * 32 + (lane & 31)];
    int rbase = blockIdx.x * 32 + 4 * (lane >> 5);
    int col0 = wave * 32 + (lane & 31);
#pragma unroll
    for (int reg = 0; reg < 16; reg++) {
        int row = rbase + (reg & 3) + 8 * (reg >> 2);
        if (row < N) {
            float v = acc[reg] + bv;
            if (H16OUT) {
                v = fmaxf(v, 0.f);
                ((__half*)outp)[(long)row * (NT * 32) + col0] = __float2half_rn(v);
            } else {
                ((float*)outp)[(long)row * (NT * 32) + col0] = v;
            }
        }
    }
}

extern "C" void kernel_launch(void* const* d_in, const int* in_sizes, int n_in,
                              void* d_out, int out_size, void* d_ws, size_t ws_size,
                              hipStream_t stream) {
    const float* x  = (const float*)d_in[0];
    const int*  src = (const int*)d_in[1];
    const int*  dst = (const int*)d_in[2];
    const float* W1 = (const float*)d_in[3];   // [384][128]
    const float* b1 = (const float*)d_in[4];
    const float* W2 = (const float*)d_in[5];   // [384][64]
    const float* b2 = (const float*)d_in[6];
    float* out = (float*)d_out;
    const int E  = in_sizes[1] / R;
    const int RE = in_sizes[1];
    const int nb = (RE + CHUNK - 1) / CHUNK;      // 293 edge chunks
    const int L  = 2 * NBKT * nb;                 // ~86k
    const int nb1 = (L + 1023) / 1024;            // ~85

    char* ws = (char*)d_ws;
    size_t off = 0;
    auto alloc = [&](size_t bytes) -> void* {
        void* p = ws + off;
        off += (bytes + 255) & ~(size_t)255;
        return p;
    };
    float* bsum1    = (float*)alloc(HID * 4);
    float* bsum2    = (float*)alloc(OUT * 4);
    float* rs_in    = (float*)alloc((size_t)M * 4);
    float* rs_out   = (float*)alloc((size_t)M * 4);
    int*   row_ptr  = (int*)alloc((size_t)(M + 1) * 4);
    int*   bh       = (int*)alloc((size_t)L * 4);
    int*   scanv    = (int*)alloc((size_t)L * 4);
    int*   partials = (int*)alloc((size_t)nb1 * 4);
    unsigned* esrc  = (unsigned*)alloc((size_t)RE * 4);
    __half* F1      = (__half*)alloc((size_t)4 * KB * 64 * 8 * 2);
    __half* F2      = (__half*)alloc((size_t)2 * KB * 64 * 8 * 2);
    int*   ebd      = (int*)alloc((size_t)RE * 4);
    unsigned short* ebs = (unsigned short*)alloc((size_t)RE * 2);
    __half* x16     = (__half*)alloc((size_t)N * IN * 2);
    __half* H16     = (__half*)alloc((size_t)N * HID * 2);

    prep_kernel<<<1 + WPK_B + (CVT_N4 + 255) / 256, 256, 0, stream>>>(
        x, W1, W2, b1, b2, (uint2*)x16, F1, F2, bsum1, bsum2);
    p1_kernel<<<nb, 256, 0, stream>>>(src, dst, E, RE, nb, bh);
    scan1_kernel<<<nb1, 1024, 0, stream>>>(bh, scanv, partials, L);
    scan2_kernel<<<1, 256, 0, stream>>>(partials, nb1);
    p3_kernel<<<nb, 256, 0, stream>>>(src, dst, E, RE, nb, scanv, partials, ebd, ebs);
    pbs_kernel<<<NBKT, 1024, 0, stream>>>(scanv, partials, nb, RE, ebs, rs_out);
    pbd_kernel<<<NBKT, 1024, 0, stream>>>(scanv, partials, nb, RE, ebd, rs_out,
                                          row_ptr, rs_in, esrc);

    const int fb = (N + 31) / 32;             // 1563 fused blocks

    // layer 1: H16 = fp16(relu(bsum1 + agg(x16) @ W1))
    fused_kernel<4, true><<<fb, 256, 0, stream>>>(x16, rs_in, rs_out, row_ptr,
                                                  esrc, F1, bsum1, H16);
    // layer 2: out = bsum2 + agg(H16) @ W2
    fused_kernel<2, false><<<fb, 256, 0, stream>>>(H16, rs_in, rs_out, row_ptr,
                                                   esrc, F2, bsum2, out);
}

// Round 12
// 399.366 us; speedup vs baseline: 1.3975x; 1.3975x over previous
//
#include <hip/hip_runtime.h>
#include <hip/hip_fp16.h>

// RGCN: out = hetero(relu(hetero(x, W1,b1)), W2,b2)
// Aggregation commutes with @W_r: Z[n] = [rs_in_r[n]*(sum_e rs_out_r[s]*feat[s] + self)]_r,
// layer = bias + Z(Nx384) @ W(384xWC), W in MFMA B-frag layout (fp16 32x32x16).
// R12 = R10 structure (R11's gather+GEMM fusion cut wave count 8x -> latency-bound
// at 1.4 TB/s; REVERTED. Lesson: for latency-bound gathers TLP is the resource).
// Tweaks: gather 16-edge unroll (8 row-loads in flight/lane; MLP depth sets gather
// rate: 2->2.83, 4->3.31 TB/s), BK 512 (pbs/pbd grid 293 blocks -> full CU cover).
// CSR build: radix partition, zero global atomics (device atomics ~32B fabric wr each).

constexpr int N   = 50000;
constexpr int R   = 3;
constexpr int IN  = 128;
constexpr int HID = 128;
constexpr int OUT = 64;
constexpr int M   = R * N;
constexpr int BK  = 512;
constexpr int NBKT = (M + BK - 1) / BK;    // 293
constexpr int CHUNK = 8192;
constexpr int KB  = 24;                    // 384/16 k-blocks for MFMA
constexpr int CVT_N4 = N * IN / 4;         // 1.6M float4 groups
constexpr int WPK   = 6 * KB * 64;         // 9216 weight frags
constexpr int WPK_B = (WPK + 255) / 256;   // 36 blocks

typedef _Float16 half8 __attribute__((ext_vector_type(8)));
typedef float floatx16 __attribute__((ext_vector_type(16)));

// ---- prep: bsum (block 0) + wpack (blocks 1..36) + x fp32->fp16 (rest) ----
__global__ void prep_kernel(const float* __restrict__ x,
                            const float* __restrict__ W1, const float* __restrict__ W2,
                            const float* __restrict__ b1, const float* __restrict__ b2,
                            uint2* __restrict__ x16,
                            __half* __restrict__ F1, __half* __restrict__ F2,
                            float* __restrict__ bsum1, float* __restrict__ bsum2) {
    int b = blockIdx.x;
    if (b == 0) {
        int t = threadIdx.x;
        if (t < HID) bsum1[t] = b1[t] + b1[HID + t] + b1[2 * HID + t];
        if (t < OUT) bsum2[t] = b2[t] + b2[OUT + t] + b2[2 * OUT + t];
        return;
    }
    if (b <= WPK_B) {
        int idx = (b - 1) * 256 + threadIdx.x;
        if (idx < 4 * KB * 64) {
            int nt = idx / (KB * 64), rem = idx % (KB * 64);
            int kb = rem / 64, lane = rem % 64;
            int c = nt * 32 + (lane & 31);
            int k0 = kb * 16 + (lane >> 5) * 8;
            __half h[8];
#pragma unroll
            for (int j = 0; j < 8; j++) h[j] = __float2half_rn(W1[(k0 + j) * 128 + c]);
            *(uint4*)(F1 + (size_t)idx * 8) = *(uint4*)h;
        } else if (idx < 6 * KB * 64) {
            int i2 = idx - 4 * KB * 64;
            int nt = i2 / (KB * 64), rem = i2 % (KB * 64);
            int kb = rem / 64, lane = rem % 64;
            int c = nt * 32 + (lane & 31);
            int k0 = kb * 16 + (lane >> 5) * 8;
            __half h[8];
#pragma unroll
            for (int j = 0; j < 8; j++) h[j] = __float2half_rn(W2[(k0 + j) * 64 + c]);
            *(uint4*)(F2 + (size_t)i2 * 8) = *(uint4*)h;
        }
        return;
    }
    int i = (b - 1 - WPK_B) * 256 + threadIdx.x;
    if (i >= CVT_N4) return;
    float4 v = ((const float4*)x)[i];
    __half2 a = __floats2half2_rn(v.x, v.y);
    __half2 c = __floats2half2_rn(v.z, v.w);
    uint2 o;
    o.x = *(unsigned*)&a;
    o.y = *(unsigned*)&c;
    x16[i] = o;
}

// ---- P1: coarse bucket histograms per edge-chunk ----
__global__ __launch_bounds__(256) void p1_kernel(const int* __restrict__ src,
                                                 const int* __restrict__ dst,
                                                 int E, int RE, int nb,
                                                 int* __restrict__ bh) {
    __shared__ int hd[NBKT], hs[NBKT];
    for (int i = threadIdx.x; i < NBKT; i += 256) { hd[i] = 0; hs[i] = 0; }
    __syncthreads();
    int beg = blockIdx.x * CHUNK, end = min(RE, beg + CHUNK);
    for (int g = beg + (int)threadIdx.x; g < end; g += 256) {
        int rb = ((g >= E) + (g >= 2 * E)) * N;
        atomicAdd(&hd[(rb + dst[g]) >> 9], 1);
        atomicAdd(&hs[(rb + src[g]) >> 9], 1);
    }
    __syncthreads();
    for (int i = threadIdx.x; i < NBKT; i += 256) {
        bh[i * nb + blockIdx.x] = hd[i];
        bh[(NBKT + i) * nb + blockIdx.x] = hs[i];
    }
}

// ---- 2-stage exclusive scan (stage-3 folded into consumers) ----
__global__ void scan1_kernel(const int* __restrict__ in, int* __restrict__ out,
                             int* __restrict__ partials, int L) {
    __shared__ int lds[1024];
    int t = threadIdx.x;
    int idx = blockIdx.x * 1024 + t;
    int v = (idx < L) ? in[idx] : 0;
    lds[t] = v;
    __syncthreads();
    for (int off = 1; off < 1024; off <<= 1) {
        int u = (t >= off) ? lds[t - off] : 0;
        __syncthreads();
        lds[t] += u;
        __syncthreads();
    }
    if (idx < L) out[idx] = lds[t] - v;
    if (t == 1023) partials[blockIdx.x] = lds[1023];
}

__global__ void scan2_kernel(int* __restrict__ partials, int nb1) {
    __shared__ int lds[256];
    int t = threadIdx.x;
    int v = (t < nb1) ? partials[t] : 0;
    lds[t] = v;
    __syncthreads();
    for (int off = 1; off < 256; off <<= 1) {
        int u = (t >= off) ? lds[t - off] : 0;
        __syncthreads();
        lds[t] += u;
        __syncthreads();
    }
    if (t < nb1) partials[t] = lds[t] - v;
}

// ---- P3: scatter edges into bucket-sorted buffers via LDS cursors ----
// ebd[pos] = (src<<9)|(dkey&511); ebs[pos] = skey&511 (ushort)
__global__ __launch_bounds__(256) void p3_kernel(const int* __restrict__ src,
                                                 const int* __restrict__ dst,
                                                 int E, int RE, int nb,
                                                 const int* __restrict__ scanv,
                                                 const int* __restrict__ partials,
                                                 int* __restrict__ ebd,
                                                 unsigned short* __restrict__ ebs) {
    __shared__ int cd[NBKT], cs[NBKT];
    for (int i = threadIdx.x; i < NBKT; i += 256) {
        int id = i * nb + blockIdx.x;
        int is = (NBKT + i) * nb + blockIdx.x;
        cd[i] = scanv[id] + partials[id >> 10];
        cs[i] = scanv[is] + partials[is >> 10] - RE;
    }
    __syncthreads();
    int beg = blockIdx.x * CHUNK, end = min(RE, beg + CHUNK);
    for (int g = beg + (int)threadIdx.x; g < end; g += 256) {
        int rb = ((g >= E) + (g >= 2 * E)) * N;
        int s  = src[g];
        int kd = rb + dst[g];
        int pd = atomicAdd(&cd[kd >> 9], 1);
        ebd[pd] = (s << 9) | (kd & 511);
        int ks = rb + s;
        int ps = atomicAdd(&cs[ks >> 9], 1);
        ebs[ps] = (unsigned short)(ks & 511);
    }
}

// ---- PB-S: per s-bucket exact histogram -> rs_out ----
__global__ __launch_bounds__(512) void pbs_kernel(const int* __restrict__ scanv,
                                                  const int* __restrict__ partials,
                                                  int nb, int RE,
                                                  const unsigned short* __restrict__ ebs,
                                                  float* __restrict__ rs_out) {
    __shared__ int cnt[BK];
    int t = threadIdx.x;
    int k = blockIdx.x;
    int i0 = (NBKT + k) * nb;
    int segbeg = scanv[i0] + partials[i0 >> 10] - RE;
    int segend;
    if (k == NBKT - 1) segend = RE;
    else {
        int i1 = i0 + nb;
        segend = scanv[i1] + partials[i1 >> 10] - RE;
    }
    cnt[t] = 0;
    __syncthreads();
    for (int e = segbeg + t; e < segend; e += 512)
        atomicAdd(&cnt[(int)ebs[e]], 1);
    __syncthreads();
    int slot = k * BK + t;
    if (slot < M) rs_out[slot] = rsqrtf((float)(cnt[t] + 1));
}

// ---- PB-D: per d-bucket histogram -> row_ptr/rs_in, scatter coeff-packed esrc ----
__global__ __launch_bounds__(512) void pbd_kernel(const int* __restrict__ scanv,
                                                  const int* __restrict__ partials,
                                                  int nb, int RE,
                                                  const int* __restrict__ ebd,
                                                  const float* __restrict__ rs_out,
                                                  int* __restrict__ row_ptr,
                                                  float* __restrict__ rs_in,
                                                  unsigned int* __restrict__ esrc) {
    __shared__ int cnt[BK];
    __shared__ int cur[BK];
    int t = threadIdx.x;
    int k = blockIdx.x;
    int i0 = k * nb;
    int segbeg = scanv[i0] + partials[i0 >> 10];
    int segend;
    if (k == NBKT - 1) segend = RE;
    else {
        int i1 = (k + 1) * nb;
        segend = scanv[i1] + partials[i1 >> 10];
    }
    cnt[t] = 0;
    __syncthreads();
    for (int e = segbeg + t; e < segend; e += 512)
        atomicAdd(&cnt[ebd[e] & 511], 1);
    __syncthreads();
    int slot = k * BK + t;
    int c = cnt[t];
    cur[t] = c;
    __syncthreads();
    for (int off = 1; off < 512; off <<= 1) {
        int u = (t >= off) ? cur[t - off] : 0;
        __syncthreads();
        cur[t] += u;
        __syncthreads();
    }
    int excl = cur[t] - c;
    if (slot < M) {
        row_ptr[slot] = segbeg + excl;
        rs_in[slot] = rsqrtf((float)(c + 1));   // +1 self-loop
    }
    if (k == NBKT - 1 && t == 0) row_ptr[M] = RE;
    __syncthreads();
    cur[t] = segbeg + excl;
    __syncthreads();
    for (int e = segbeg + t; e < segend; e += 512) {
        int v = ebd[e];
        int key = k * BK + (v & 511);
        int r = (key >= 2 * N) + (key >= N);
        unsigned s = (unsigned)(v >> 9);
        int pos = atomicAdd(&cur[v & 511], 1);
        __half h = __float2half_rn(rs_out[r * N + s]);
        esrc[pos] = s | ((unsigned)__half_as_ushort(h) << 16);
    }
}

// ---- pair-gather, 16-edge unroll: one wave per node; half-wave per edge
// (32 lanes x uint2 = 256B row); 8 independent row loads/lane in flight;
// packed __hfma2 accumulation; cross-half reduce via shfl_xor(32). ----
__global__ __launch_bounds__(256) void gather_kernel(const __half* __restrict__ Xh,
                                                     const float* __restrict__ rs_in,
                                                     const float* __restrict__ rs_out,
                                                     const int* __restrict__ row_ptr,
                                                     const unsigned int* __restrict__ esrc,
                                                     __half* __restrict__ Z16) {
    int n = blockIdx.x * 4 + (threadIdx.x >> 6);
    if (n >= N) return;
    int lane = threadIdx.x & 63;
    int pair = lane >> 5;
    int c4 = (lane & 31) * 4;               // 4 cols per lane
    uint2 xn = *(const uint2*)(Xh + (long)n * 128 + c4);
    const __half2 z2 = __float2half2_rn(0.f);
#pragma unroll
    for (int r = 0; r < R; r++) {
        int key = r * N + n;
        __half2 acc0 = z2, acc1 = z2;
        int beg = row_ptr[key], end = row_ptr[key + 1];
        int e = beg;
        for (; e + 16 <= end; e += 16) {
            unsigned u[8];
            uint2 y[8];
#pragma unroll
            for (int j = 0; j < 8; j++) u[j] = esrc[e + 2 * j + pair];
#pragma unroll
            for (int j = 0; j < 8; j++)
                y[j] = *(const uint2*)(Xh + (long)(u[j] & 0xffffu) * 128 + c4);
#pragma unroll
            for (int j = 0; j < 8; j++) {
                __half2 cj = __half2half2(__ushort_as_half((unsigned short)(u[j] >> 16)));
                acc0 = __hfma2(*(__half2*)&y[j].x, cj, acc0);
                acc1 = __hfma2(*(__half2*)&y[j].y, cj, acc1);
            }
        }
        for (; e + 8 <= end; e += 8) {
            unsigned u[4];
            uint2 y[4];
#pragma unroll
            for (int j = 0; j < 4; j++) u[j] = esrc[e + 2 * j + pair];
#pragma unroll
            for (int j = 0; j < 4; j++)
                y[j] = *(const uint2*)(Xh + (long)(u[j] & 0xffffu) * 128 + c4);
#pragma unroll
            for (int j = 0; j < 4; j++) {
                __half2 cj = __half2half2(__ushort_as_half((unsigned short)(u[j] >> 16)));
                acc0 = __hfma2(*(__half2*)&y[j].x, cj, acc0);
                acc1 = __hfma2(*(__half2*)&y[j].y, cj, acc1);
            }
        }
        for (; e < end; e += 2) {
            int idx = e + pair;
            unsigned u = (idx < end) ? esrc[idx] : 0u;   // coeff bits 0 -> adds 0
            uint2 y = *(const uint2*)(Xh + (long)(u & 0xffffu) * 128 + c4);
            __half2 cc = __half2half2(__ushort_as_half((unsigned short)(u >> 16)));
            acc0 = __hfma2(*(__half2*)&y.x, cc, acc0);
            acc1 = __hfma2(*(__half2*)&y.y, cc, acc1);
        }
        // combine the two half-wave partials
        unsigned a0 = *(unsigned*)&acc0, a1 = *(unsigned*)&acc1;
        unsigned b0 = (unsigned)__shfl_xor((int)a0, 32, 64);
        unsigned b1 = (unsigned)__shfl_xor((int)a1, 32, 64);
        acc0 = __hadd2(acc0, *(__half2*)&b0);
        acc1 = __hadd2(acc1, *(__half2*)&b1);
        // self-loop + rs_in scale
        __half2 cs = __float2half2_rn(rs_out[key]);
        acc0 = __hfma2(*(__half2*)&xn.x, cs, acc0);
        acc1 = __hfma2(*(__half2*)&xn.y, cs, acc1);
        __half2 ri = __float2half2_rn(rs_in[key]);
        acc0 = __hmul2(acc0, ri);
        acc1 = __hmul2(acc1, ri);
        if (pair == 0) {
            uint2 o;
            o.x = *(unsigned*)&acc0;
            o.y = *(unsigned*)&acc1;
            *(uint2*)(Z16 + (long)n * 384 + r * 128 + c4) = o;
        }
    }
}

// ---- MFMA GEMM: out[N,NT*32] = bias + Z16[N,384] @ W; A-frags direct from Z16
// rows, B-frags from repacked F. 32x32x16 f16.
// C/D map: col=lane&31, row=(reg&3)+8*(reg>>2)+4*(lane>>5)  [m74/m101 verified]
template <int NT, bool H16OUT>
__global__ __launch_bounds__(256) void mfma_gemm_kernel(const __half* __restrict__ Z16,
                                                        const __half* __restrict__ F,
                                                        const float* __restrict__ bias,
                                                        void* __restrict__ outp) {
    int wave = threadIdx.x >> 6, lane = threadIdx.x & 63;
    int m0 = blockIdx.x * 128 + wave * 32;
    int mrow = m0 + (lane & 31);
    int mr = min(mrow, N - 1);
    const half8* A = (const half8*)(Z16 + (long)mr * 384 + (lane >> 5) * 8);
    const half8* B = (const half8*)F;
    floatx16 acc[NT];
#pragma unroll
    for (int i = 0; i < NT; i++)
#pragma unroll
        for (int j = 0; j < 16; j++) acc[i][j] = 0.f;

    half8 a = A[0];
    for (int kb = 0; kb < KB; kb++) {
        half8 an = (kb < KB - 1) ? A[(kb + 1) * 2] : a;
#pragma unroll
        for (int nt = 0; nt < NT; nt++) {
            half8 b = B[(nt * KB + kb) * 64 + lane];
            acc[nt] = __builtin_amdgcn_mfma_f32_32x32x16_f16(a, b, acc[nt], 0, 0, 0);
        }
        a = an;
    }

    float bv[NT];
#pragma unroll
    for (int nt = 0; nt < NT; nt++) bv[nt] = bias[nt * 32 + (lane & 31)];
    int rbase = m0 + 4 * (lane >> 5);
    int col0 = lane & 31;
#pragma unroll
    for (int nt = 0; nt < NT; nt++) {
#pragma unroll
        for (int reg = 0; reg < 16; reg++) {
            int row = rbase + (reg & 3) + 8 * (reg >> 2);
            if (row < N) {
                float v = acc[nt][reg] + bv[nt];
                if (H16OUT) {
                    v = fmaxf(v, 0.f);
                    ((__half*)outp)[(long)row * (NT * 32) + nt * 32 + col0] = __float2half_rn(v);
                } else {
                    ((float*)outp)[(long)row * (NT * 32) + nt * 32 + col0] = v;
                }
            }
        }
    }
}

extern "C" void kernel_launch(void* const* d_in, const int* in_sizes, int n_in,
                              void* d_out, int out_size, void* d_ws, size_t ws_size,
                              hipStream_t stream) {
    const float* x  = (const float*)d_in[0];
    const int*  src = (const int*)d_in[1];
    const int*  dst = (const int*)d_in[2];
    const float* W1 = (const float*)d_in[3];   // [384][128]
    const float* b1 = (const float*)d_in[4];
    const float* W2 = (const float*)d_in[5];   // [384][64]
    const float* b2 = (const float*)d_in[6];
    float* out = (float*)d_out;
    const int E  = in_sizes[1] / R;
    const int RE = in_sizes[1];
    const int nb = (RE + CHUNK - 1) / CHUNK;      // 293 edge chunks
    const int L  = 2 * NBKT * nb;                 // ~172k
    const int nb1 = (L + 1023) / 1024;            // ~168

    char* ws = (char*)d_ws;
    size_t off = 0;
    auto alloc = [&](size_t bytes) -> void* {
        void* p = ws + off;
        off += (bytes + 255) & ~(size_t)255;
        return p;
    };
    float* bsum1    = (float*)alloc(HID * 4);
    float* bsum2    = (float*)alloc(OUT * 4);
    float* rs_in    = (float*)alloc((size_t)M * 4);
    float* rs_out   = (float*)alloc((size_t)M * 4);
    int*   row_ptr  = (int*)alloc((size_t)(M + 1) * 4);
    int*   bh       = (int*)alloc((size_t)L * 4);
    int*   scanv    = (int*)alloc((size_t)L * 4);
    int*   partials = (int*)alloc((size_t)nb1 * 4);
    unsigned* esrc  = (unsigned*)alloc((size_t)RE * 4);
    __half* F1      = (__half*)alloc((size_t)4 * KB * 64 * 8 * 2);
    __half* F2      = (__half*)alloc((size_t)2 * KB * 64 * 8 * 2);
    // region A: ebd (9.6MB) + ebs (4.8MB) during build, Z16 (38.4MB) afterwards
    char*  regA     = (char*)alloc((size_t)N * 384 * 2);
    int*   ebd      = (int*)regA;
    unsigned short* ebs = (unsigned short*)(regA + (size_t)RE * 4);
    __half* Z16     = (__half*)regA;
    __half* x16     = (__half*)alloc((size_t)N * IN * 2);
    __half* H16     = (__half*)alloc((size_t)N * HID * 2);

    prep_kernel<<<1 + WPK_B + (CVT_N4 + 255) / 256, 256, 0, stream>>>(
        x, W1, W2, b1, b2, (uint2*)x16, F1, F2, bsum1, bsum2);
    p1_kernel<<<nb, 256, 0, stream>>>(src, dst, E, RE, nb, bh);
    scan1_kernel<<<nb1, 1024, 0, stream>>>(bh, scanv, partials, L);
    scan2_kernel<<<1, 256, 0, stream>>>(partials, nb1);
    p3_kernel<<<nb, 256, 0, stream>>>(src, dst, E, RE, nb, scanv, partials, ebd, ebs);
    pbs_kernel<<<NBKT, 512, 0, stream>>>(scanv, partials, nb, RE, ebs, rs_out);
    pbd_kernel<<<NBKT, 512, 0, stream>>>(scanv, partials, nb, RE, ebd, rs_out,
                                         row_ptr, rs_in, esrc);

    const int ab  = (N + 3) / 4;              // 12500 gather blocks
    const int ggb = (N + 127) / 128;          // 391 gemm blocks

    // layer 1: Z = gather(x16); H16 = fp16(relu(bsum1 + Z @ W1))
    gather_kernel<<<ab, 256, 0, stream>>>(x16, rs_in, rs_out, row_ptr, esrc, Z16);
    mfma_gemm_kernel<4, true><<<ggb, 256, 0, stream>>>(Z16, F1, bsum1, H16);
    // layer 2: Z = gather(H16); out = bsum2 + Z @ W2
    gather_kernel<<<ab, 256, 0, stream>>>(H16, rs_in, rs_out, row_ptr, esrc, Z16);
    mfma_gemm_kernel<2, false><<<ggb, 256, 0, stream>>>(Z16, F2, bsum2, out);
}

// Round 13
// 364.006 us; speedup vs baseline: 1.5333x; 1.0971x over previous
//
#include <hip/hip_runtime.h>
#include <hip/hip_fp16.h>

// RGCN: out = hetero(relu(hetero(x, W1,b1)), W2,b2)
// Layer 1 (IN=HID=128): fused 3-relation gather of x16 -> Z(Nx384), then
//   H16 = fp16(relu(bsum1 + Z @ W1)) via MFMA (W in B-frag layout).
// Layer 2 (OUT=64 < HID): GEMM-FIRST — Y2_r = H16 @ W2_r (fp16, 3x Nx64),
//   then gather_out sums coeff*Y2_r rows (128B/edge, half of gather-first)
//   + bias -> fp32 out. R12 lesson: gather is fabric-byte-bound with
//   efficiency dropping at small requests; MLP>4 loads/lane adds nothing.
// BK=1024 (R12's 512 cost ~10us in build). CSR build: radix partition,
// zero global atomics (device atomics ~32B fabric write each).

constexpr int N   = 50000;
constexpr int R   = 3;
constexpr int IN  = 128;
constexpr int HID = 128;
constexpr int OUT = 64;
constexpr int M   = R * N;
constexpr int BK  = 1024;
constexpr int NBKT = (M + BK - 1) / BK;    // 147
constexpr int CHUNK = 8192;
constexpr int KB  = 24;                    // 384/16 k-blocks for MFMA
constexpr int CVT_N4 = N * IN / 4;         // 1.6M float4 groups
constexpr int WPK   = 6 * KB * 64;         // 9216 weight frags
constexpr int WPK_B = (WPK + 255) / 256;   // 36 blocks

typedef _Float16 half8 __attribute__((ext_vector_type(8)));
typedef float floatx16 __attribute__((ext_vector_type(16)));

// ---- prep: bsum (block 0) + wpack (blocks 1..36) + x fp32->fp16 (rest) ----
__global__ void prep_kernel(const float* __restrict__ x,
                            const float* __restrict__ W1, const float* __restrict__ W2,
                            const float* __restrict__ b1, const float* __restrict__ b2,
                            uint2* __restrict__ x16,
                            __half* __restrict__ F1, __half* __restrict__ F2,
                            float* __restrict__ bsum1, float* __restrict__ bsum2) {
    int b = blockIdx.x;
    if (b == 0) {
        int t = threadIdx.x;
        if (t < HID) bsum1[t] = b1[t] + b1[HID + t] + b1[2 * HID + t];
        if (t < OUT) bsum2[t] = b2[t] + b2[OUT + t] + b2[2 * OUT + t];
        return;
    }
    if (b <= WPK_B) {
        int idx = (b - 1) * 256 + threadIdx.x;
        if (idx < 4 * KB * 64) {
            int nt = idx / (KB * 64), rem = idx % (KB * 64);
            int kb = rem / 64, lane = rem % 64;
            int c = nt * 32 + (lane & 31);
            int k0 = kb * 16 + (lane >> 5) * 8;
            __half h[8];
#pragma unroll
            for (int j = 0; j < 8; j++) h[j] = __float2half_rn(W1[(k0 + j) * 128 + c]);
            *(uint4*)(F1 + (size_t)idx * 8) = *(uint4*)h;
        } else if (idx < 6 * KB * 64) {
            int i2 = idx - 4 * KB * 64;
            int nt = i2 / (KB * 64), rem = i2 % (KB * 64);
            int kb = rem / 64, lane = rem % 64;
            int c = nt * 32 + (lane & 31);
            int k0 = kb * 16 + (lane >> 5) * 8;
            __half h[8];
#pragma unroll
            for (int j = 0; j < 8; j++) h[j] = __float2half_rn(W2[(k0 + j) * 64 + c]);
            *(uint4*)(F2 + (size_t)i2 * 8) = *(uint4*)h;
        }
        return;
    }
    int i = (b - 1 - WPK_B) * 256 + threadIdx.x;
    if (i >= CVT_N4) return;
    float4 v = ((const float4*)x)[i];
    __half2 a = __floats2half2_rn(v.x, v.y);
    __half2 c = __floats2half2_rn(v.z, v.w);
    uint2 o;
    o.x = *(unsigned*)&a;
    o.y = *(unsigned*)&c;
    x16[i] = o;
}

// ---- P1: coarse bucket histograms per edge-chunk ----
__global__ __launch_bounds__(256) void p1_kernel(const int* __restrict__ src,
                                                 const int* __restrict__ dst,
                                                 int E, int RE, int nb,
                                                 int* __restrict__ bh) {
    __shared__ int hd[NBKT], hs[NBKT];
    for (int i = threadIdx.x; i < NBKT; i += 256) { hd[i] = 0; hs[i] = 0; }
    __syncthreads();
    int beg = blockIdx.x * CHUNK, end = min(RE, beg + CHUNK);
    for (int g = beg + (int)threadIdx.x; g < end; g += 256) {
        int rb = ((g >= E) + (g >= 2 * E)) * N;
        atomicAdd(&hd[(rb + dst[g]) >> 10], 1);
        atomicAdd(&hs[(rb + src[g]) >> 10], 1);
    }
    __syncthreads();
    for (int i = threadIdx.x; i < NBKT; i += 256) {
        bh[i * nb + blockIdx.x] = hd[i];
        bh[(NBKT + i) * nb + blockIdx.x] = hs[i];
    }
}

// ---- 2-stage exclusive scan (stage-3 folded into consumers) ----
__global__ void scan1_kernel(const int* __restrict__ in, int* __restrict__ out,
                             int* __restrict__ partials, int L) {
    __shared__ int lds[1024];
    int t = threadIdx.x;
    int idx = blockIdx.x * 1024 + t;
    int v = (idx < L) ? in[idx] : 0;
    lds[t] = v;
    __syncthreads();
    for (int off = 1; off < 1024; off <<= 1) {
        int u = (t >= off) ? lds[t - off] : 0;
        __syncthreads();
        lds[t] += u;
        __syncthreads();
    }
    if (idx < L) out[idx] = lds[t] - v;
    if (t == 1023) partials[blockIdx.x] = lds[1023];
}

__global__ void scan2_kernel(int* __restrict__ partials, int nb1) {
    __shared__ int lds[256];
    int t = threadIdx.x;
    int v = (t < nb1) ? partials[t] : 0;
    lds[t] = v;
    __syncthreads();
    for (int off = 1; off < 256; off <<= 1) {
        int u = (t >= off) ? lds[t - off] : 0;
        __syncthreads();
        lds[t] += u;
        __syncthreads();
    }
    if (t < nb1) partials[t] = lds[t] - v;
}

// ---- P3: scatter edges into bucket-sorted buffers via LDS cursors ----
// ebd[pos] = (src<<10)|(dkey&1023); ebs[pos] = skey&1023 (ushort)
__global__ __launch_bounds__(256) void p3_kernel(const int* __restrict__ src,
                                                 const int* __restrict__ dst,
                                                 int E, int RE, int nb,
                                                 const int* __restrict__ scanv,
                                                 const int* __restrict__ partials,
                                                 int* __restrict__ ebd,
                                                 unsigned short* __restrict__ ebs) {
    __shared__ int cd[NBKT], cs[NBKT];
    for (int i = threadIdx.x; i < NBKT; i += 256) {
        int id = i * nb + blockIdx.x;
        int is = (NBKT + i) * nb + blockIdx.x;
        cd[i] = scanv[id] + partials[id >> 10];
        cs[i] = scanv[is] + partials[is >> 10] - RE;
    }
    __syncthreads();
    int beg = blockIdx.x * CHUNK, end = min(RE, beg + CHUNK);
    for (int g = beg + (int)threadIdx.x; g < end; g += 256) {
        int rb = ((g >= E) + (g >= 2 * E)) * N;
        int s  = src[g];
        int kd = rb + dst[g];
        int pd = atomicAdd(&cd[kd >> 10], 1);
        ebd[pd] = (s << 10) | (kd & 1023);
        int ks = rb + s;
        int ps = atomicAdd(&cs[ks >> 10], 1);
        ebs[ps] = (unsigned short)(ks & 1023);
    }
}

// ---- PB-S: per s-bucket exact histogram -> rs_out ----
__global__ __launch_bounds__(1024) void pbs_kernel(const int* __restrict__ scanv,
                                                   const int* __restrict__ partials,
                                                   int nb, int RE,
                                                   const unsigned short* __restrict__ ebs,
                                                   float* __restrict__ rs_out) {
    __shared__ int cnt[BK];
    int t = threadIdx.x;
    int k = blockIdx.x;
    int i0 = (NBKT + k) * nb;
    int segbeg = scanv[i0] + partials[i0 >> 10] - RE;
    int segend;
    if (k == NBKT - 1) segend = RE;
    else {
        int i1 = i0 + nb;
        segend = scanv[i1] + partials[i1 >> 10] - RE;
    }
    cnt[t] = 0;
    __syncthreads();
    for (int e = segbeg + t; e < segend; e += 1024)
        atomicAdd(&cnt[(int)ebs[e]], 1);
    __syncthreads();
    int slot = k * BK + t;
    if (slot < M) rs_out[slot] = rsqrtf((float)(cnt[t] + 1));
}

// ---- PB-D: per d-bucket histogram -> row_ptr/rs_in, scatter coeff-packed esrc ----
__global__ __launch_bounds__(1024) void pbd_kernel(const int* __restrict__ scanv,
                                                   const int* __restrict__ partials,
                                                   int nb, int RE,
                                                   const int* __restrict__ ebd,
                                                   const float* __restrict__ rs_out,
                                                   int* __restrict__ row_ptr,
                                                   float* __restrict__ rs_in,
                                                   unsigned int* __restrict__ esrc) {
    __shared__ int cnt[BK];
    __shared__ int cur[BK];
    int t = threadIdx.x;
    int k = blockIdx.x;
    int i0 = k * nb;
    int segbeg = scanv[i0] + partials[i0 >> 10];
    int segend;
    if (k == NBKT - 1) segend = RE;
    else {
        int i1 = (k + 1) * nb;
        segend = scanv[i1] + partials[i1 >> 10];
    }
    cnt[t] = 0;
    __syncthreads();
    for (int e = segbeg + t; e < segend; e += 1024)
        atomicAdd(&cnt[ebd[e] & 1023], 1);
    __syncthreads();
    int slot = k * BK + t;
    int c = cnt[t];
    cur[t] = c;
    __syncthreads();
    for (int off = 1; off < 1024; off <<= 1) {
        int u = (t >= off) ? cur[t - off] : 0;
        __syncthreads();
        cur[t] += u;
        __syncthreads();
    }
    int excl = cur[t] - c;
    if (slot < M) {
        row_ptr[slot] = segbeg + excl;
        rs_in[slot] = rsqrtf((float)(c + 1));   // +1 self-loop
    }
    if (k == NBKT - 1 && t == 0) row_ptr[M] = RE;
    __syncthreads();
    cur[t] = segbeg + excl;
    __syncthreads();
    for (int e = segbeg + t; e < segend; e += 1024) {
        int v = ebd[e];
        int key = k * BK + (v & 1023);
        int r = (key >= 2 * N) + (key >= N);
        unsigned s = (unsigned)(v >> 10);
        int pos = atomicAdd(&cur[v & 1023], 1);
        __half h = __float2half_rn(rs_out[r * N + s]);
        esrc[pos] = s | ((unsigned)__half_as_ushort(h) << 16);
    }
}

// ---- layer-1 pair-gather, 16-edge unroll: one wave per node; half-wave per
// edge (32 lanes x uint2 = 256B row); __hfma2 accumulation; shfl_xor(32) combine. ----
__global__ __launch_bounds__(256) void gather_kernel(const __half* __restrict__ Xh,
                                                     const float* __restrict__ rs_in,
                                                     const float* __restrict__ rs_out,
                                                     const int* __restrict__ row_ptr,
                                                     const unsigned int* __restrict__ esrc,
                                                     __half* __restrict__ Z16) {
    int n = blockIdx.x * 4 + (threadIdx.x >> 6);
    if (n >= N) return;
    int lane = threadIdx.x & 63;
    int pair = lane >> 5;
    int c4 = (lane & 31) * 4;               // 4 cols per lane
    uint2 xn = *(const uint2*)(Xh + (long)n * 128 + c4);
    const __half2 z2 = __float2half2_rn(0.f);
#pragma unroll
    for (int r = 0; r < R; r++) {
        int key = r * N + n;
        __half2 acc0 = z2, acc1 = z2;
        int beg = row_ptr[key], end = row_ptr[key + 1];
        int e = beg;
        for (; e + 16 <= end; e += 16) {
            unsigned u[8];
            uint2 y[8];
#pragma unroll
            for (int j = 0; j < 8; j++) u[j] = esrc[e + 2 * j + pair];
#pragma unroll
            for (int j = 0; j < 8; j++)
                y[j] = *(const uint2*)(Xh + (long)(u[j] & 0xffffu) * 128 + c4);
#pragma unroll
            for (int j = 0; j < 8; j++) {
                __half2 cj = __half2half2(__ushort_as_half((unsigned short)(u[j] >> 16)));
                acc0 = __hfma2(*(__half2*)&y[j].x, cj, acc0);
                acc1 = __hfma2(*(__half2*)&y[j].y, cj, acc1);
            }
        }
        for (; e + 8 <= end; e += 8) {
            unsigned u[4];
            uint2 y[4];
#pragma unroll
            for (int j = 0; j < 4; j++) u[j] = esrc[e + 2 * j + pair];
#pragma unroll
            for (int j = 0; j < 4; j++)
                y[j] = *(const uint2*)(Xh + (long)(u[j] & 0xffffu) * 128 + c4);
#pragma unroll
            for (int j = 0; j < 4; j++) {
                __half2 cj = __half2half2(__ushort_as_half((unsigned short)(u[j] >> 16)));
                acc0 = __hfma2(*(__half2*)&y[j].x, cj, acc0);
                acc1 = __hfma2(*(__half2*)&y[j].y, cj, acc1);
            }
        }
        for (; e < end; e += 2) {
            int idx = e + pair;
            unsigned u = (idx < end) ? esrc[idx] : 0u;   // coeff bits 0 -> adds 0
            uint2 y = *(const uint2*)(Xh + (long)(u & 0xffffu) * 128 + c4);
            __half2 cc = __half2half2(__ushort_as_half((unsigned short)(u >> 16)));
            acc0 = __hfma2(*(__half2*)&y.x, cc, acc0);
            acc1 = __hfma2(*(__half2*)&y.y, cc, acc1);
        }
        unsigned a0 = *(unsigned*)&acc0, a1 = *(unsigned*)&acc1;
        unsigned b0 = (unsigned)__shfl_xor((int)a0, 32, 64);
        unsigned b1 = (unsigned)__shfl_xor((int)a1, 32, 64);
        acc0 = __hadd2(acc0, *(__half2*)&b0);
        acc1 = __hadd2(acc1, *(__half2*)&b1);
        __half2 cs = __float2half2_rn(rs_out[key]);
        acc0 = __hfma2(*(__half2*)&xn.x, cs, acc0);
        acc1 = __hfma2(*(__half2*)&xn.y, cs, acc1);
        __half2 ri = __float2half2_rn(rs_in[key]);
        acc0 = __hmul2(acc0, ri);
        acc1 = __hmul2(acc1, ri);
        if (pair == 0) {
            uint2 o;
            o.x = *(unsigned*)&acc0;
            o.y = *(unsigned*)&acc1;
            *(uint2*)(Z16 + (long)n * 384 + r * 128 + c4) = o;
        }
    }
}

// ---- layer-1 MFMA GEMM: H16 = fp16(relu(bias + Z16[N,384] @ W1)); A-frags
// direct from Z16 rows, B-frags from F1. 32x32x16 f16.
// C/D map: col=lane&31, row=(reg&3)+8*(reg>>2)+4*(lane>>5)  [m74/m101 verified]
__global__ __launch_bounds__(256) void mfma_gemm1_kernel(const __half* __restrict__ Z16,
                                                         const __half* __restrict__ F,
                                                         const float* __restrict__ bias,
                                                         __half* __restrict__ H16) {
    int wave = threadIdx.x >> 6, lane = threadIdx.x & 63;
    int m0 = blockIdx.x * 128 + wave * 32;
    int mr = min(m0 + (lane & 31), N - 1);
    const half8* A = (const half8*)(Z16 + (long)mr * 384 + (lane >> 5) * 8);
    const half8* B = (const half8*)F;
    floatx16 acc[4];
#pragma unroll
    for (int i = 0; i < 4; i++)
#pragma unroll
        for (int j = 0; j < 16; j++) acc[i][j] = 0.f;

    half8 a = A[0];
    for (int kb = 0; kb < KB; kb++) {
        half8 an = (kb < KB - 1) ? A[(kb + 1) * 2] : a;
#pragma unroll
        for (int nt = 0; nt < 4; nt++) {
            half8 b = B[(nt * KB + kb) * 64 + lane];
            acc[nt] = __builtin_amdgcn_mfma_f32_32x32x16_f16(a, b, acc[nt], 0, 0, 0);
        }
        a = an;
    }
    float bv[4];
#pragma unroll
    for (int nt = 0; nt < 4; nt++) bv[nt] = bias[nt * 32 + (lane & 31)];
    int rbase = m0 + 4 * (lane >> 5);
    int col0 = lane & 31;
#pragma unroll
    for (int nt = 0; nt < 4; nt++) {
#pragma unroll
        for (int reg = 0; reg < 16; reg++) {
            int row = rbase + (reg & 3) + 8 * (reg >> 2);
            if (row < N) {
                float v = fmaxf(acc[nt][reg] + bv[nt], 0.f);
                H16[(long)row * 128 + nt * 32 + col0] = __float2half_rn(v);
            }
        }
    }
}

// ---- layer-2 GEMM-first: Y2[r][N][64] = H16[N,128] @ W2_r (fp16 out, no bias).
// F2 kb-layout: relation r's K-chunk is kb = r*8 + kbr. blockIdx.y = r. ----
__global__ __launch_bounds__(256) void mfma_gemmY_kernel(const __half* __restrict__ H16,
                                                         const __half* __restrict__ F,
                                                         __half* __restrict__ Y2) {
    int wave = threadIdx.x >> 6, lane = threadIdx.x & 63;
    int r = blockIdx.y;
    int m0 = blockIdx.x * 128 + wave * 32;
    int mr = min(m0 + (lane & 31), N - 1);
    const half8* A = (const half8*)(H16 + (long)mr * 128 + (lane >> 5) * 8);
    const half8* B = (const half8*)F;
    floatx16 acc[2];
#pragma unroll
    for (int i = 0; i < 2; i++)
#pragma unroll
        for (int j = 0; j < 16; j++) acc[i][j] = 0.f;

#pragma unroll
    for (int kbr = 0; kbr < 8; kbr++) {
        half8 a = A[kbr * 2];
#pragma unroll
        for (int nt = 0; nt < 2; nt++) {
            half8 b = B[(nt * KB + r * 8 + kbr) * 64 + lane];
            acc[nt] = __builtin_amdgcn_mfma_f32_32x32x16_f16(a, b, acc[nt], 0, 0, 0);
        }
    }
    int rbase = m0 + 4 * (lane >> 5);
    int col0 = lane & 31;
    __half* Yr = Y2 + (long)r * N * 64;
#pragma unroll
    for (int nt = 0; nt < 2; nt++) {
#pragma unroll
        for (int reg = 0; reg < 16; reg++) {
            int row = rbase + (reg & 3) + 8 * (reg >> 2);
            if (row < N)
                Yr[(long)row * 64 + nt * 32 + col0] = __float2half_rn(acc[nt][reg]);
        }
    }
}

// ---- layer-2 gather: out[n] = bsum2 + sum_r rs_in*(sum_e coeff*Y2_r[s] + rs_out*Y2_r[n]).
// 128B rows: 32 lanes x half2 (dword); pair = lane>>5 handles alternate edges;
// 16-edge unroll (8 dword loads in flight/lane). fp32 out. ----
__global__ __launch_bounds__(256) void gather_out_kernel(const __half* __restrict__ Y2,
                                                         const float* __restrict__ rs_in,
                                                         const float* __restrict__ rs_out,
                                                         const int* __restrict__ row_ptr,
                                                         const unsigned int* __restrict__ esrc,
                                                         const float* __restrict__ bias,
                                                         float* __restrict__ outp) {
    int n = blockIdx.x * 4 + (threadIdx.x >> 6);
    if (n >= N) return;
    int lane = threadIdx.x & 63;
    int pair = lane >> 5;
    int c2 = (lane & 31) * 2;               // 2 cols per lane
    const __half2 z2 = __float2half2_rn(0.f);
    float2 tot = ((const float2*)bias)[lane & 31];
#pragma unroll
    for (int r = 0; r < R; r++) {
        int key = r * N + n;
        const __half* Yr = Y2 + (long)r * N * 64;
        __half2 acc = z2;
        int beg = row_ptr[key], end = row_ptr[key + 1];
        int e = beg;
        for (; e + 16 <= end; e += 16) {
            unsigned u[8];
            __half2 y[8];
#pragma unroll
            for (int j = 0; j < 8; j++) u[j] = esrc[e + 2 * j + pair];
#pragma unroll
            for (int j = 0; j < 8; j++)
                y[j] = *(const __half2*)(Yr + (long)(u[j] & 0xffffu) * 64 + c2);
#pragma unroll
            for (int j = 0; j < 8; j++)
                acc = __hfma2(y[j], __half2half2(__ushort_as_half((unsigned short)(u[j] >> 16))), acc);
        }
        for (; e + 8 <= end; e += 8) {
            unsigned u[4];
            __half2 y[4];
#pragma unroll
            for (int j = 0; j < 4; j++) u[j] = esrc[e + 2 * j + pair];
#pragma unroll
            for (int j = 0; j < 4; j++)
                y[j] = *(const __half2*)(Yr + (long)(u[j] & 0xffffu) * 64 + c2);
#pragma unroll
            for (int j = 0; j < 4; j++)
                acc = __hfma2(y[j], __half2half2(__ushort_as_half((unsigned short)(u[j] >> 16))), acc);
        }
        for (; e < end; e += 2) {
            int idx = e + pair;
            unsigned u = (idx < end) ? esrc[idx] : 0u;
            __half2 y = *(const __half2*)(Yr + (long)(u & 0xffffu) * 64 + c2);
            acc = __hfma2(y, __half2half2(__ushort_as_half((unsigned short)(u >> 16))), acc);
        }
        unsigned a0 = *(unsigned*)&acc;
        unsigned b0 = (unsigned)__shfl_xor((int)a0, 32, 64);
        acc = __hadd2(acc, *(__half2*)&b0);
        // self-loop
        __half2 ys = *(const __half2*)(Yr + (long)n * 64 + c2);
        acc = __hfma2(ys, __float2half2_rn(rs_out[key]), acc);
        float2 f = __half22float2(acc);
        float ri = rs_in[key];
        tot.x += ri * f.x;
        tot.y += ri * f.y;
    }
    if (pair == 0) *(float2*)(outp + (long)n * 64 + c2) = tot;
}

extern "C" void kernel_launch(void* const* d_in, const int* in_sizes, int n_in,
                              void* d_out, int out_size, void* d_ws, size_t ws_size,
                              hipStream_t stream) {
    const float* x  = (const float*)d_in[0];
    const int*  src = (const int*)d_in[1];
    const int*  dst = (const int*)d_in[2];
    const float* W1 = (const float*)d_in[3];   // [384][128]
    const float* b1 = (const float*)d_in[4];
    const float* W2 = (const float*)d_in[5];   // [384][64]
    const float* b2 = (const float*)d_in[6];
    float* out = (float*)d_out;
    const int E  = in_sizes[1] / R;
    const int RE = in_sizes[1];
    const int nb = (RE + CHUNK - 1) / CHUNK;      // 293 edge chunks
    const int L  = 2 * NBKT * nb;                 // ~86k
    const int nb1 = (L + 1023) / 1024;            // ~85

    char* ws = (char*)d_ws;
    size_t off = 0;
    auto alloc = [&](size_t bytes) -> void* {
        void* p = ws + off;
        off += (bytes + 255) & ~(size_t)255;
        return p;
    };
    float* bsum1    = (float*)alloc(HID * 4);
    float* bsum2    = (float*)alloc(OUT * 4);
    float* rs_in    = (float*)alloc((size_t)M * 4);
    float* rs_out   = (float*)alloc((size_t)M * 4);
    int*   row_ptr  = (int*)alloc((size_t)(M + 1) * 4);
    int*   bh       = (int*)alloc((size_t)L * 4);
    int*   scanv    = (int*)alloc((size_t)L * 4);
    int*   partials = (int*)alloc((size_t)nb1 * 4);
    unsigned* esrc  = (unsigned*)alloc((size_t)RE * 4);
    __half* F1      = (__half*)alloc((size_t)4 * KB * 64 * 8 * 2);
    __half* F2      = (__half*)alloc((size_t)2 * KB * 64 * 8 * 2);
    // region A: ebd(9.6MB)+ebs(4.8MB) during build; Z16 (38.4MB) for layer 1;
    // Y2 (19.2MB) for layer 2 (Z16 dead after gemm1).
    char*  regA     = (char*)alloc((size_t)N * 384 * 2);
    int*   ebd      = (int*)regA;
    unsigned short* ebs = (unsigned short*)(regA + (size_t)RE * 4);
    __half* Z16     = (__half*)regA;
    __half* Y2      = (__half*)regA;
    __half* x16     = (__half*)alloc((size_t)N * IN * 2);
    __half* H16     = (__half*)alloc((size_t)N * HID * 2);

    prep_kernel<<<1 + WPK_B + (CVT_N4 + 255) / 256, 256, 0, stream>>>(
        x, W1, W2, b1, b2, (uint2*)x16, F1, F2, bsum1, bsum2);
    p1_kernel<<<nb, 256, 0, stream>>>(src, dst, E, RE, nb, bh);
    scan1_kernel<<<nb1, 1024, 0, stream>>>(bh, scanv, partials, L);
    scan2_kernel<<<1, 256, 0, stream>>>(partials, nb1);
    p3_kernel<<<nb, 256, 0, stream>>>(src, dst, E, RE, nb, scanv, partials, ebd, ebs);
    pbs_kernel<<<NBKT, 1024, 0, stream>>>(scanv, partials, nb, RE, ebs, rs_out);
    pbd_kernel<<<NBKT, 1024, 0, stream>>>(scanv, partials, nb, RE, ebd, rs_out,
                                          row_ptr, rs_in, esrc);

    const int ab  = (N + 3) / 4;              // 12500 gather blocks
    const int ggb = (N + 127) / 128;          // 391 gemm blocks

    // layer 1: Z = gather(x16); H16 = fp16(relu(bsum1 + Z @ W1))
    gather_kernel<<<ab, 256, 0, stream>>>(x16, rs_in, rs_out, row_ptr, esrc, Z16);
    mfma_gemm1_kernel<<<ggb, 256, 0, stream>>>(Z16, F1, bsum1, H16);
    // layer 2 (GEMM-first): Y2_r = H16 @ W2_r; out = bsum2 + agg(Y2)
    mfma_gemmY_kernel<<<dim3(ggb, R), 256, 0, stream>>>(H16, F2, Y2);
    gather_out_kernel<<<ab, 256, 0, stream>>>(Y2, rs_in, rs_out, row_ptr, esrc,
                                              bsum2, out);
}